// Round 2
// baseline (116.947 us; speedup 1.0000x reference)
//
#include <hip/hip_runtime.h>
#include <stdint.h>

// ---------------------------------------------------------------------------
// CritiGraph distance kernel: bit-exact reproduction of the JAX reference
// (jax_threefry_partitionable=True path, verified absmax 0.0 rounds 1-2 of
// the previous session).
//
// Round-4 structure (LDS-transpose):
//   - One block per t-row (grid 2048, block 256 = 16 tp x 16 jl).
//   - h == jl is per-thread constant: flip bit, mask, and threefry counter
//     base hoisted out of the 16-iteration j loop.
//   - d1/d2 scattered into a 32.8 KB LDS row buffer [513][16]; after one
//     __syncthreads the row is streamed out as coalesced 16B-aligned
//     nontemporal float4 stores (full 128B lines, write-once).
//     (native ext_vector_type float4 — HIP's float4 class is rejected by
//     __builtin_nontemporal_store.)
//   - Channel pairs (iperm[j], iperm[j+257]) packed into a compile-time
//     __constant__ u32 table; loaded once per thread, statically indexed.
//   - ori/norm gathered once per (t,tp) instead of 64x.
// ---------------------------------------------------------------------------

#define H_   16
#define TP_  16
#define K_   16
#define T_   2048
#define NC   513                       // 2*H*K + 1

typedef float f32x4 __attribute__((ext_vector_type(4)));

struct TFPair { uint32_t a, b; };

__host__ __device__ constexpr uint32_t rotl32(uint32_t x, int r) {
  return (x << r) | (x >> (32 - r));
}

__host__ __device__ constexpr TFPair tf2x32(uint32_t k0, uint32_t k1,
                                            uint32_t x0, uint32_t x1) {
  uint32_t ks0 = k0, ks1 = k1, ks2 = k0 ^ k1 ^ 0x1BD11BDAu;
  x0 += ks0; x1 += ks1;
  x0 += x1; x1 = rotl32(x1, 13); x1 ^= x0;
  x0 += x1; x1 = rotl32(x1, 15); x1 ^= x0;
  x0 += x1; x1 = rotl32(x1, 26); x1 ^= x0;
  x0 += x1; x1 = rotl32(x1,  6); x1 ^= x0;
  x0 += ks1; x1 += ks2 + 1u;
  x0 += x1; x1 = rotl32(x1, 17); x1 ^= x0;
  x0 += x1; x1 = rotl32(x1, 29); x1 ^= x0;
  x0 += x1; x1 = rotl32(x1, 16); x1 ^= x0;
  x0 += x1; x1 = rotl32(x1, 24); x1 ^= x0;
  x0 += ks2; x1 += ks0 + 2u;
  x0 += x1; x1 = rotl32(x1, 13); x1 ^= x0;
  x0 += x1; x1 = rotl32(x1, 15); x1 ^= x0;
  x0 += x1; x1 = rotl32(x1, 26); x1 ^= x0;
  x0 += x1; x1 = rotl32(x1,  6); x1 ^= x0;
  x0 += ks0; x1 += ks1 + 3u;
  x0 += x1; x1 = rotl32(x1, 17); x1 ^= x0;
  x0 += x1; x1 = rotl32(x1, 29); x1 ^= x0;
  x0 += x1; x1 = rotl32(x1, 16); x1 ^= x0;
  x0 += x1; x1 = rotl32(x1, 24); x1 ^= x0;
  x0 += ks1; x1 += ks2 + 4u;
  x0 += x1; x1 = rotl32(x1, 13); x1 ^= x0;
  x0 += x1; x1 = rotl32(x1, 15); x1 ^= x0;
  x0 += x1; x1 = rotl32(x1, 26); x1 ^= x0;
  x0 += x1; x1 = rotl32(x1,  6); x1 ^= x0;
  x0 += ks2; x1 += ks0 + 5u;
  return {x0, x1};
}

// ---- compile-time key derivation (jax.random.key(42) == (0,42)) -----------
constexpr TFPair KM = tf2x32(0u, 42u, 0u, 0u);   // kmask = split(key)[0]
constexpr TFPair KP = tf2x32(0u, 42u, 0u, 1u);   // kperm = split(key)[1]
constexpr TFPair C2 = tf2x32(KM.a, KM.b, 0u, 1u);   // k2 of split(kmask)
constexpr uint32_t KLO0 = C2.a, KLO1 = C2.b;
constexpr TFPair SB = tf2x32(KP.a, KP.b, 0u, 1u);   // subkey of split(kperm)
constexpr uint32_t KSUB0 = SB.a, KSUB1 = SB.b;

// ---- compile-time permutation: inv_perm[m] = stable rank of sortkey[m] ----
struct Keys { uint32_t v[NC]; };
constexpr Keys make_keys() {
  Keys k{};
  for (int i = 0; i < NC; ++i) {
    TFPair r = tf2x32(KSUB0, KSUB1, 0u, (uint32_t)i);
    k.v[i] = r.a ^ r.b;          // 32-bit random_bits, partitionable: hi^lo
  }
  return k;
}
constexpr Keys KEYS = make_keys();

#define PART_SZ 33
struct Part { int v[PART_SZ]; };
constexpr Part make_part(int lo) {
  Part p{};
  for (int m = lo; m < lo + PART_SZ && m < NC; ++m) {
    uint32_t km = KEYS.v[m];
    int rank = 0;
    for (int j = 0; j < NC; ++j) {
      uint32_t kj = KEYS.v[j];
      if (kj < km || (kj == km && j < m)) ++rank;
    }
    p.v[m - lo] = rank;
  }
  return p;
}
// 16 separate constexpr variables: each gets its own constexpr step budget.
constexpr Part PT0  = make_part(0),   PT1  = make_part(33),
               PT2  = make_part(66),  PT3  = make_part(99),
               PT4  = make_part(132), PT5  = make_part(165),
               PT6  = make_part(198), PT7  = make_part(231),
               PT8  = make_part(264), PT9  = make_part(297),
               PT10 = make_part(330), PT11 = make_part(363),
               PT12 = make_part(396), PT13 = make_part(429),
               PT14 = make_part(462), PT15 = make_part(495);

struct IPerm { int v[NC]; };
constexpr IPerm merge_parts() {
  IPerm r{};
  const Part* ps[16] = {&PT0, &PT1, &PT2,  &PT3,  &PT4,  &PT5,  &PT6,  &PT7,
                        &PT8, &PT9, &PT10, &PT11, &PT12, &PT13, &PT14, &PT15};
  for (int c = 0; c < 16; ++c)
    for (int i = 0; i < PART_SZ; ++i) {
      int m = c * PART_SZ + i;
      if (m < NC) r.v[m] = ps[c]->v[i];
    }
  return r;
}
constexpr IPerm IPERM = merge_parts();
constexpr int C_ORI = IPERM.v[256];     // output channel of the 'ori' column

// Packed channel-pair table: low16 = channel of +result (j), high16 = channel
// of -result (j+257).  Indexed by j = jl*16 + jj.
struct CTab { uint32_t v[256]; };
constexpr CTab make_ctab() {
  CTab c{};
  for (int j = 0; j < 256; ++j)
    c.v[j] = (uint32_t)IPERM.v[j] | ((uint32_t)IPERM.v[j + 257] << 16);
  return c;
}
constexpr CTab CTAB = make_ctab();
__device__ __constant__ CTab d_ctab = CTAB;

// ---- dist kernel: one block per t-row, 256 threads = 16 tp x 16 jl --------
__global__ __launch_bounds__(256, 4) void dist_kernel(
    const int* __restrict__ locations, const int* __restrict__ pos_idx,
    const float* __restrict__ norm, float* __restrict__ out) {
  __shared__ __align__(16) float buf[NC * TP_];   // 513*16 floats = 32832 B

  const int t   = (int)blockIdx.x;
  const int tid = (int)threadIdx.x;
  const int tp  = tid & 15;
  const int jl  = tid >> 4;                 // == h for all 16 j's of this thread

  const int   ori  = locations[pos_idx[t] * TP_ + tp];
  const float nm   = norm[t];
  const float nm16 = nm * 0.0625f;

  // the 'ori' channel: dist(ori,ori) = (1 - 1/16)*norm
  if (tid < 16) buf[C_ORI * TP_ + tid] = 0.9375f * nm;

  // per-thread packed channel pairs (statically indexed -> registers)
  uint32_t ct[16];
#pragma unroll
  for (int i = 0; i < 16; ++i) ct[i] = d_ctab.v[(jl << 4) + i];

  // hoisted per-thread constants (h == jl)
  const uint32_t flip_h = 1u << jl;
  const uint32_t mask_h = flip_h - 1u;
  const uint32_t base   = (uint32_t)(((jl * T_ + t) * K_) * TP_ + tp);
  const uint32_t ao     = (uint32_t)(ori < 0 ? -ori : ori);

#pragma unroll
  for (int jj = 0; jj < 16; ++jj) {
    // flat index into (H, T, K, TP) mask tensor; k == jj
    const TFPair r = tf2x32(KLO0, KLO1, 0u, base + (uint32_t)(jj * TP_));
    // flip bit h, xor the (2^h-1)-masked random bits
    const uint32_t fm = flip_h ^ (r.b & mask_h);
    const int v = ori ^ (int)fm;

    // dist(v, ori) = sign(v)*sign(ori) * (1 - bitlen(|v|^|ori|+1)/16) * norm
    const uint32_t sgbit = ((uint32_t)(v ^ ori)) & 0x80000000u;
    const uint32_t av = (uint32_t)(v < 0 ? -v : v);
    const uint32_t x  = (av ^ ao) + 1u;                  // <= 2^16, exact f32
    const int e = 32 - __clz((int)x);                    // bit length
    const float f  = nm - (float)e * nm16;               // (1 - e/16)*nm
    const float d1 = __uint_as_float(__float_as_uint(f) ^ sgbit);
    // dist(-v, ori): |v| unchanged, sign flips unless v==0
    const float d2 = (v == 0) ? d1
                   : __uint_as_float(__float_as_uint(d1) ^ 0x80000000u);

    const uint32_t pr = ct[jj];
    buf[(pr & 0xffffu) * TP_ + tp] = d1;
    buf[(pr >> 16)     * TP_ + tp] = d2;
  }

  __syncthreads();

  // stream the whole 32.8 KB row out, fully coalesced, write-once
  const f32x4* __restrict__ b4 = (const f32x4*)buf;
  f32x4* __restrict__ o4 = (f32x4*)(out + (size_t)t * (NC * TP_));
#pragma unroll
  for (int it = 0; it < 8; ++it)
    __builtin_nontemporal_store(b4[(it << 8) + tid], o4 + (it << 8) + tid);
  if (tid < 4)                                           // 2052 = 8*256 + 4
    __builtin_nontemporal_store(b4[2048 + tid], o4 + 2048 + tid);
}

extern "C" void kernel_launch(void* const* d_in, const int* in_sizes, int n_in,
                              void* d_out, int out_size, void* d_ws, size_t ws_size,
                              hipStream_t stream) {
  const int*   locations = (const int*)d_in[0];
  const int*   pos_idx   = (const int*)d_in[1];
  const float* norm      = (const float*)d_in[2];
  float* out = (float*)d_out;

  hipLaunchKernelGGL(dist_kernel, dim3(T_), dim3(256), 0, stream,
                     locations, pos_idx, norm, out);
}